// Round 1
// 218.287 us; speedup vs baseline: 1.0518x; 1.0518x over previous
//
#include <hip/hip_runtime.h>
#include <hip/hip_bf16.h>

#define L_SEQ 40
#define B_SZ  16
#define V_SZ  10000
#define V_PAD 10240
#define NPAIR 780
#define NROWP 784                 // 780 pairs + 1 init row + 3 pad "pairs"
#define M_ROWS (NROWP * B_SZ)     // 12544 rows = 98 strips of 128

typedef __attribute__((ext_vector_type(4))) float f32x4;
typedef __attribute__((ext_vector_type(4))) int   i32x4;
typedef __attribute__((ext_vector_type(8))) int   i32x8;

// ---------------------------------------------------------------------------
// float -> OCP e4m3fn. Prefer HW cvt; hand-rolled RNE fallback.
// ---------------------------------------------------------------------------
#if __has_builtin(__builtin_amdgcn_cvt_pk_fp8_f32)
__device__ __forceinline__ unsigned int pack4_fp8(float x0, float x1, float x2, float x3) {
    int lo = __builtin_amdgcn_cvt_pk_fp8_f32(x0, x1, 0, false);
    int full = __builtin_amdgcn_cvt_pk_fp8_f32(x2, x3, lo, true);
    return (unsigned int)full;
}
#else
__device__ __forceinline__ unsigned char f2e4m3(float f) {
    unsigned u = __float_as_uint(f);
    unsigned s = (u >> 24) & 0x80u;
    if ((u & 0x7FFFFFFFu) == 0) return (unsigned char)s;
    int E = (int)((u >> 23) & 0xFF) - 127 + 7;
    unsigned m = u & 0x7FFFFFu;
    if (E >= 16) return (unsigned char)(s | 0x7E);
    if (E >= 1) {
        unsigned keep = m >> 20, rest = m & 0xFFFFFu;
        keep += (rest > 0x80000u) || (rest == 0x80000u && (keep & 1));
        if (keep == 8) { keep = 0; E++; if (E >= 16) return (unsigned char)(s | 0x7E); }
        return (unsigned char)(s | (E << 3) | keep);
    }
    int shift = 1 - E;
    if (shift > 10) return (unsigned char)s;
    unsigned full = 0x800000u | m;
    unsigned sh = 20 + shift;
    unsigned keep = full >> sh, rem = full & ((1u << sh) - 1), half = 1u << (sh - 1);
    keep += (rem > half) || (rem == half && (keep & 1));
    if (keep >= 8) return (unsigned char)(s | (1 << 3));
    return (unsigned char)(s | keep);
}
__device__ __forceinline__ unsigned int pack4_fp8(float x0, float x1, float x2, float x3) {
    return (unsigned int)f2e4m3(x0) | ((unsigned int)f2e4m3(x1) << 8)
         | ((unsigned int)f2e4m3(x2) << 16) | ((unsigned int)f2e4m3(x3) << 24);
}
#endif

// Layout note: X and WbT are PLAIN row-major fp8 [row][k], 256 B per row.
// The MX-scaled MFMA (16x16x128) fragment is linear per lane: lane l holds
// row l&15, K-bytes (l>>4)*32 .. +31 — no byte permutation needed.

// ---------------------------------------------------------------------------
// K1: fused prep. [0,2560): transpose Ww2 -> WwT fp32 [10240,256] + WbT fp8
//     (linear row-major); [2560,2880): UV = h @ {Wt1,Ww1} halves; rest: zero
//     rowsum.
// ---------------------------------------------------------------------------
__global__ __launch_bounds__(256) void prep_kernel(
        const float* __restrict__ Ww2, float* __restrict__ WwT,
        unsigned char* __restrict__ WbT,
        const float* __restrict__ h, const float* __restrict__ Wt1,
        const float* __restrict__ Ww1, float* __restrict__ UV,
        float* __restrict__ rowsum) {
    const int bx = blockIdx.x;
    const int t = threadIdx.x;
    __shared__ float tile[32][33];
    __shared__ float hs[8 * 512];
    if (bx < 2560) {
        int v0 = (bx % 320) * 32;
        int K8 = bx / 320;           // k-tile index, k0 = K8*32
        int k0 = K8 * 32;
        int tx = t & 31, ty = t >> 5;   // 32 x 8
#pragma unroll
        for (int r = 0; r < 4; r++) {
            int k = k0 + ty + r * 8;
            int v = v0 + tx;
            tile[ty + r * 8][tx] = (v < V_SZ) ? Ww2[k * V_SZ + v] : 0.0f;   // tile[k][v]
        }
        __syncthreads();
        // fp32 transposed write
#pragma unroll
        for (int r = 0; r < 4; r++) {
            int vrow = ty + r * 8;
            WwT[(v0 + vrow) * 256 + (k0 + tx)] = tile[tx][vrow];
        }
        // fp8 write: thread -> (col v2, 4 consecutive k), linear layout
        int v2 = t >> 3;                 // 0..31
        int kq = 4 * (t & 7);            // local k base 0..28
        unsigned int pk = pack4_fp8(tile[kq][v2], tile[kq + 1][v2],
                                    tile[kq + 2][v2], tile[kq + 3][v2]);
        ((unsigned int*)WbT)[(v0 + v2) * 64 + K8 * 8 + (t & 7)] = pk;
    } else if (bx < 2880) {
        int ub = bx - 2560;
        int which = ub / 80;         // 0:Ut 1:Vt 2:Uw 3:Vw
        int m0 = (ub % 80) * 8;
        const float4* src = (const float4*)(h + (size_t)m0 * 512);
        float4* dst4 = (float4*)hs;
#pragma unroll
        for (int v = 0; v < 4; v++) dst4[v * 256 + t] = src[v * 256 + t];
        __syncthreads();
        const float* W = ((which < 2) ? Wt1 : Ww1) + ((which & 1) ? 512 * 256 : 0);
        float acc[8] = {};
        for (int f = 0; f < 512; f += 4) {
            float w0 = W[(f + 0) * 256 + t];
            float w1 = W[(f + 1) * 256 + t];
            float w2 = W[(f + 2) * 256 + t];
            float w3 = W[(f + 3) * 256 + t];
#pragma unroll
            for (int r = 0; r < 8; r++) {
                acc[r] += hs[r * 512 + f] * w0 + hs[r * 512 + f + 1] * w1
                        + hs[r * 512 + f + 2] * w2 + hs[r * 512 + f + 3] * w3;
            }
        }
        float* dst = UV + ((size_t)which * 640 + m0) * 256;
#pragma unroll
        for (int r = 0; r < 8; r++) dst[r * 256 + t] = acc[r];
    } else {
        int idx = (bx - 2880) * 256 + t;
        if (idx < M_ROWS) rowsum[idx] = 0.0f;
    }
}

// ---------------------------------------------------------------------------
// K2: per (pair,b) row: X = fp8(tanh(Uw[i]+Vw[j]+bw1)) linear row-major;
//     tlog/glog fp32 exact. One wave per row; p==780 is the init cell.
// ---------------------------------------------------------------------------
__global__ void build_rows(const float* __restrict__ UV,
                           const int* __restrict__ sentence,
                           const float* __restrict__ bt1,
                           const float* __restrict__ bw1,
                           const float* __restrict__ Wt2,
                           const float* __restrict__ bt2,
                           const float* __restrict__ WwT,
                           const float* __restrict__ bw2,
                           unsigned char* __restrict__ X,
                           float* __restrict__ tlog,
                           float* __restrict__ glog) {
    int w = blockIdx.x * 4 + (threadIdx.x >> 6);
    int lane = threadIdx.x & 63;
    int p = w >> 4, b = w & 15;
    int i = 0, j = 0;
    if (p < NPAIR) {
        int rem = p, len = L_SEQ - 1;
        while (rem >= len) { rem -= len; len--; i++; }
        j = i + 1 + rem;
    }
    int j1 = (j + 1 < L_SEQ) ? j + 1 : L_SEQ - 1;
    int tgt = sentence[j1 * B_SZ + b];
    const float4 ut = ((const float4*)(UV + 0 * 640 * 256 + (i * B_SZ + b) * 256))[lane];
    const float4 vt = ((const float4*)(UV + 1 * 640 * 256 + (j * B_SZ + b) * 256))[lane];
    const float4 uw = ((const float4*)(UV + 2 * 640 * 256 + (i * B_SZ + b) * 256))[lane];
    const float4 vw = ((const float4*)(UV + 3 * 640 * 256 + (j * B_SZ + b) * 256))[lane];
    const float4 bt = ((const float4*)bt1)[lane];
    const float4 bw = ((const float4*)bw1)[lane];
    const float4 w2 = ((const float4*)Wt2)[lane];
    const float4 wc = ((const float4*)(WwT + (size_t)tgt * 256))[lane];
    float xt0 = tanhf(ut.x + vt.x + bt.x), xt1 = tanhf(ut.y + vt.y + bt.y);
    float xt2 = tanhf(ut.z + vt.z + bt.z), xt3 = tanhf(ut.w + vt.w + bt.w);
    float xw0 = tanhf(uw.x + vw.x + bw.x), xw1 = tanhf(uw.y + vw.y + bw.y);
    float xw2 = tanhf(uw.z + vw.z + bw.z), xw3 = tanhf(uw.w + vw.w + bw.w);
    // linear: lane covers k = 4*lane .. 4*lane+3
    ((unsigned int*)X)[w * 64 + lane] = pack4_fp8(xw0, xw1, xw2, xw3);
    float td = xt0 * w2.x + xt1 * w2.y + xt2 * w2.z + xt3 * w2.w;
    float gd = xw0 * wc.x + xw1 * wc.y + xw2 * wc.z + xw3 * wc.w;
#pragma unroll
    for (int off = 32; off >= 1; off >>= 1) {
        td += __shfl_xor(td, off);
        gd += __shfl_xor(gd, off);
    }
    if (lane == 0) {
        tlog[w] = td + bt2[0];
        glog[w] = gd + bw2[tgt];
    }
}

// ---------------------------------------------------------------------------
// K3: MX-scaled fp8 GEMM (16x16x128, unit scales => exact fp8 dot products
// at 2.27x the non-scaled fp8 rate) + fused sum-exp, A-in-registers.
// Grid (8 col-groups, 98 row-strips), 4 waves/block (2 row-halves x 2
// col-halves). Wave = 64 rows x 64 cols. The wave's whole A panel
// (64 rows x K=256 fp8) lives in 64 VGPRs (linear layout: lane holds row
// l&15 of each 16-row block, K-bytes l4*32..+31 per 128-K block), loaded
// once from global. K-loop reads ONLY B from LDS: 16 ds_read_b128 + 32
// scaled MFMA per 128-col iteration. B tiles (128 cols x 256 B = 32 KB)
// double-buffered (64 KB LDS, 2 blocks/CU) via global_load_lds w=16 with
// XOR-granule swizzle (2-way max = free). 10 iterations of 128 cols; one
// barrier per iteration; exp into per-lane PS regs; one butterfly +
// 16 atomics per wave at kernel end.
// ---------------------------------------------------------------------------
__global__ __launch_bounds__(256, 2) void big_gemm(
        const unsigned char* __restrict__ X,
        const unsigned char* __restrict__ WbT,
        const float* __restrict__ bw2,
        float* __restrict__ rowsum) {
    __shared__ unsigned char Bs[2][128 * 256];   // 2 x 32 KB
    const int t = threadIdx.x;
    const int wid = t >> 6, lane = t & 63;
    const int l15 = lane & 15, l4 = lane >> 4;
    const int rh = wid >> 1, ch = wid & 1;
    const int g = blockIdx.x;                    // col group: 1280 cols
    const int row0 = blockIdx.y * 128 + rh * 64; // wave's 64 rows

    auto dmaB = [&](int buf, int it) {
        const unsigned char* Bg = WbT + (size_t)(g * 1280 + it * 128) * 256;
#pragma unroll
        for (int q = 0; q < 8; q++) {
            int base = (wid * 8 + q) * 1024;     // wave-uniform dest
            int F = base + lane * 16;            // this lane's dest byte
            int cc = F >> 8;                     // dest col within tile
            int s = (F >> 4) & 15;               // dest granule slot
            int srcg = s ^ (cc & 15);            // swizzled source granule
            __builtin_amdgcn_global_load_lds(
                (const __attribute__((address_space(1))) unsigned int*)(Bg + cc * 256 + (srcg << 4)),
                (__attribute__((address_space(3))) unsigned int*)(&Bs[buf][0] + base),
                16, 0, 0);
        }
    };

    dmaB(0, 0);

    // ---- A panel: 64 rows x K=256 in 64 VGPRs (linear, 32 B/lane/block)
    i32x8 apan[4][2];
    {
        const unsigned char* Ag = X + (size_t)row0 * 256;
#pragma unroll
        for (int mi = 0; mi < 4; mi++)
#pragma unroll
            for (int kb = 0; kb < 2; kb++)
                apan[mi][kb] = *(const i32x8*)(Ag + (mi * 16 + l15) * 256 + kb * 128 + l4 * 32);
    }
    __syncthreads();   // drains DMA for iter 0 too

    float PS[4][4] = {};

#pragma unroll 1
    for (int it = 0; it < 10; it++) {
        if (it < 9) dmaB((it + 1) & 1, it + 1);
        const unsigned char* Bb = &Bs[it & 1][0];
        f32x4 acc[4][4] = {};
#pragma unroll
        for (int kb = 0; kb < 2; kb++) {
            i32x8 b[4];
#pragma unroll
            for (int ni = 0; ni < 4; ni++) {
                int cc = ch * 64 + ni * 16 + l15;
                int g0 = kb * 8 + l4 * 2;        // first 16-B granule of lane's 32 B
                i32x4 lo = *(const i32x4*)(Bb + cc * 256 + (((g0 + 0) ^ (cc & 15)) << 4));
                i32x4 hi = *(const i32x4*)(Bb + cc * 256 + (((g0 + 1) ^ (cc & 15)) << 4));
                i32x8 bv = {lo.x, lo.y, lo.z, lo.w, hi.x, hi.y, hi.z, hi.w};
                b[ni] = bv;
            }
#pragma unroll
            for (int mi = 0; mi < 4; mi++)
#pragma unroll
                for (int ni = 0; ni < 4; ni++)
                    acc[mi][ni] = __builtin_amdgcn_mfma_scale_f32_16x16x128_f8f6f4(
                        apan[mi][kb], b[ni], acc[mi][ni],
                        0, 0,                  // cbsz=fp8(e4m3), blgp=fp8(e4m3)
                        0, 0x7F7F7F7F,         // scale_a opsel, e8m0 unit scales
                        0, 0x7F7F7F7F);        // scale_b opsel, e8m0 unit scales
        }
        // ---- epilogue: exp(logit + bias) into per-lane partials ----
#pragma unroll
        for (int ni = 0; ni < 4; ni++) {
            int col = g * 1280 + it * 128 + ch * 64 + ni * 16 + l15;
            float bias = (col < V_SZ) ? bw2[col] : -__builtin_inff();
#pragma unroll
            for (int mi = 0; mi < 4; mi++)
#pragma unroll
                for (int r = 0; r < 4; r++)
                    PS[mi][r] += __expf(acc[mi][ni][r] + bias);
        }
        __syncthreads();
    }
    // ---- one butterfly + atomics per wave ----
#pragma unroll
    for (int mi = 0; mi < 4; mi++)
#pragma unroll
        for (int r = 0; r < 4; r++) {
            float v = PS[mi][r];
            v += __shfl_xor(v, 1); v += __shfl_xor(v, 2);
            v += __shfl_xor(v, 4); v += __shfl_xor(v, 8);
            if (l15 == 0)
                atomicAdd(&rowsum[row0 + mi * 16 + l4 * 4 + r], v);
        }
}

// ---------------------------------------------------------------------------
// K4: build tables in LDS + CKY DP. 16 blocks (one per batch), 1024 thr,
// 16 lanes per (i) cell parallelize the split loop.
// ---------------------------------------------------------------------------
__global__ __launch_bounds__(1024) void dp_kernel(const float* __restrict__ tlog,
                          const float* __restrict__ glog,
                          const float* __restrict__ rowsum,
                          float* __restrict__ out) {
    __shared__ float Tl[1600], SHWl[1600], REl[1600];
    const int t = threadIdx.x;
    const int b = blockIdx.x;
    const float NEGINF = -__builtin_inff();
    for (int idx = t; idx < 1600; idx += 1024) {
        Tl[idx] = NEGINF; SHWl[idx] = NEGINF; REl[idx] = NEGINF;
    }
    __syncthreads();
    for (int p = t; p < NPAIR; p += 1024) {
        int i = 0, rem = p, len = L_SEQ - 1;
        while (rem >= len) { rem -= len; len--; i++; }
        int j = i + 1 + rem;
        int row = p * 16 + b;
        float tl = tlog[row];
        float re_v = (tl >= 0.f) ? -log1pf(__expf(-tl)) : (tl - log1pf(__expf(tl)));
        float sh_v = (tl <= 0.f) ? -log1pf(__expf(tl)) : (-tl - log1pf(__expf(-tl)));
        float wlp = glog[row] - __logf(rowsum[row]);
        SHWl[i * 40 + j] = sh_v + wlp;
        REl[i * 40 + j] = re_v;
    }
    if (t == 0) {
        int row = NPAIR * 16 + b;           // init cell
        Tl[0 * 40 + 1] = glog[row] - __logf(rowsum[row]);
    }
    if (t >= 1 && t <= 38) Tl[t * 40 + t + 1] = 0.f;
    __syncthreads();
    const int tg = t >> 4, li = t & 15;
    for (int gap = 2; gap <= L_SEQ - 1; gap++) {
        int n_i = L_SEQ - gap;
        float m = NEGINF, s = 0.f;
        int i = tg, j = tg + gap;
        if (tg < n_i) {
            for (int k = i + 1 + li; k < j; k += 16) {
                float v = Tl[i * 40 + k] + Tl[k * 40 + j]
                        + SHWl[i * 40 + k] + REl[k * 40 + j];
                if (v > m) { s = s * __expf(m - v) + 1.f; m = v; }
                else s += __expf(v - m);
            }
        }
#pragma unroll
        for (int off = 1; off < 16; off <<= 1) {
            float mo = __shfl_xor(m, off), so = __shfl_xor(s, off);
            float M = fmaxf(m, mo);
            float sn = 0.f;
            if (m > NEGINF) sn += s * __expf(m - M);
            if (mo > NEGINF) sn += so * __expf(mo - M);
            m = M; s = sn;
        }
        if (tg < n_i && li == 0) Tl[i * 40 + j] = m + __logf(s);
        __syncthreads();
    }
    if (t == 0) out[b] = Tl[39];
}

// ---------------------------------------------------------------------------
extern "C" void kernel_launch(void* const* d_in, const int* in_sizes, int n_in,
                              void* d_out, int out_size, void* d_ws, size_t ws_size,
                              hipStream_t stream) {
    const float* h        = (const float*)d_in[0];
    const int*   sentence = (const int*)d_in[1];
    const float* Wt1      = (const float*)d_in[2];
    const float* bt1      = (const float*)d_in[3];
    const float* Wt2      = (const float*)d_in[4];
    const float* bt2      = (const float*)d_in[5];
    const float* Ww1      = (const float*)d_in[6];
    const float* bw1      = (const float*)d_in[7];
    const float* Ww2      = (const float*)d_in[8];
    const float* bw2      = (const float*)d_in[9];
    float* out = (float*)d_out;

    char* ws = (char*)d_ws;
    size_t off = 0;
    float* UV = (float*)(ws + off);                    off += 4ull * 640 * 256 * 4;
    unsigned char* X = (unsigned char*)(ws + off);     off += (size_t)M_ROWS * 256;
    unsigned char* WbT = (unsigned char*)(ws + off);   off += (size_t)V_PAD * 256;
    float* WwT = (float*)(ws + off);                   off += (size_t)V_PAD * 256 * 4;
    float* rowsum = (float*)(ws + off);                off += (size_t)M_ROWS * 4;
    float* tlog = (float*)(ws + off);                  off += (size_t)M_ROWS * 4;
    float* glog = (float*)(ws + off);                  off += (size_t)M_ROWS * 4;

    const int zero_blocks = (M_ROWS + 255) / 256;      // 49
    prep_kernel<<<2880 + zero_blocks, 256, 0, stream>>>(
        Ww2, WwT, WbT, h, Wt1, Ww1, UV, rowsum);
    build_rows<<<M_ROWS / 4, 256, 0, stream>>>(UV, sentence, bt1, bw1, Wt2, bt2,
                                               WwT, bw2, X, tlog, glog);
    big_gemm<<<dim3(8, 98), 256, 0, stream>>>(X, WbT, bw2, rowsum);
    dp_kernel<<<16, 1024, 0, stream>>>(tlog, glog, rowsum, out);
}